// Round 10
// baseline (86.558 us; speedup 1.0000x reference)
//
#include <hip/hip_runtime.h>
#include <hip/hip_bf16.h>

typedef __bf16 bf16_t;
typedef __attribute__((ext_vector_type(8))) __bf16 bf16x8;
typedef __attribute__((ext_vector_type(4))) __bf16 bf16x4;
typedef __attribute__((ext_vector_type(4))) float f32x4;

#define AS1 __attribute__((address_space(1)))
#define AS3 __attribute__((address_space(3)))

__device__ __forceinline__ void gload_lds16(const void* g, void* l) {
  __builtin_amdgcn_global_load_lds((const AS1 void*)g, (AS3 void*)l, 16, 0, 0);
}

// ---------------- prep: vectorized transposes, 64x64 tiles ----------------
// blocks 0..255: 4 weights fp32[512][512] -> bf16 wT[n][k]
// blocks 256..1279: x fp32 [B][C][S] -> xr bf16 [B][S][C]
// Read: float4/lane; LDS fp32 [64][69] (transposed read = 2-way bank, free);
// write: bf16x8/lane (16B, 128B rows).
__global__ void __launch_bounds__(256) prep_kernel(
    const float* __restrict__ x, const float* __restrict__ w0,
    const float* __restrict__ w1, const float* __restrict__ w2,
    const float* __restrict__ w3, bf16_t* __restrict__ xr, bf16_t* __restrict__ t0,
    bf16_t* __restrict__ t1, bf16_t* __restrict__ t2, bf16_t* __restrict__ t3) {
  __shared__ float tile[64][69];
  int t = blockIdx.x;
  const float* src;
  bf16_t* dst;
  int ld_src, ld_dst, R0, C0;
  if (t < 256) {
    int z = t >> 6, rem = t & 63;
    src = (z == 0) ? w0 : (z == 1) ? w1 : (z == 2) ? w2 : w3;
    dst = (z == 0) ? t0 : (z == 1) ? t1 : (z == 2) ? t2 : t3;
    ld_src = 512; ld_dst = 512;
    R0 = (rem >> 3) * 64;  // k-dim
    C0 = (rem & 7) * 64;   // n-dim
  } else {
    t -= 256;
    int b = t >> 7, rem = t & 127;
    src = x + (size_t)b * 512 * 1024;
    dst = xr + (size_t)b * 1024 * 512;
    ld_src = 1024; ld_dst = 512;
    R0 = (rem >> 4) * 64;  // c-dim (rows of src)
    C0 = (rem & 15) * 64;  // s-dim
  }
  const int tid = threadIdx.x;
  const int rl = tid >> 4;         // 0..15
  const int cl = (tid & 15) * 4;   // float4 col offset
#pragma unroll
  for (int p = 0; p < 4; ++p) {
    int r = p * 16 + rl;
    float4 v = *(const float4*)(src + (size_t)(R0 + r) * ld_src + C0 + cl);
    tile[r][cl + 0] = v.x;
    tile[r][cl + 1] = v.y;
    tile[r][cl + 2] = v.z;
    tile[r][cl + 3] = v.w;
  }
  __syncthreads();
  const int kk = tid & 7;    // 8-chunk of r
  const int cw = tid >> 3;   // 0..31 (+32*pass): output row (C-dim)
#pragma unroll
  for (int p = 0; p < 2; ++p) {
    int c = p * 32 + cw;
    bf16x8 o;
#pragma unroll
    for (int j = 0; j < 8; ++j) o[j] = (bf16_t)tile[kk * 8 + j][c];
    *(bf16x8*)(dst + (size_t)(C0 + c) * ld_dst + R0 + kk * 8) = o;
  }
}

// ------- 128x128xK=512 NT-GEMM mainloop, QUAD-buffered, depth-2 (round-7) -------
__device__ __forceinline__ void gemm_nt_128x128_p4(const bf16_t* __restrict__ Abase,
                                                   const bf16_t* __restrict__ Bbase,
                                                   bf16_t (*As)[128 * 32],
                                                   bf16_t (*Bs)[128 * 32],
                                                   f32x4 acc[4][4]) {
  const int tid = threadIdx.x;
  const int lane = tid & 63;
  const int wid = tid >> 6;
  const int wr = wid >> 1, wc = wid & 1;
  const int lrow = lane & 15;
  const int kgrp = lane >> 4;
  const int r0 = tid >> 2;
  const int cb = (tid & 3) * 16;

#pragma unroll
  for (int p = 0; p < 2; ++p) {
    const int kt = p * 32;
#pragma unroll
    for (int j = 0; j < 2; ++j) {
      int row = j * 64 + r0;
      gload_lds16((const char*)(Abase + row * 512 + kt) + cb, (char*)As[p] + row * 64 + cb);
    }
#pragma unroll
    for (int j = 0; j < 2; ++j) {
      int row = j * 64 + r0;
      gload_lds16((const char*)(Bbase + row * 512 + kt) + cb, (char*)Bs[p] + row * 64 + cb);
    }
  }

  for (int t = 0; t < 16; ++t) {
    const int cur = t & 3;
    if (t < 14) {
      const int nxt = (t + 2) & 3;
      const int kt = (t + 2) * 32;
#pragma unroll
      for (int j = 0; j < 2; ++j) {
        int row = j * 64 + r0;
        gload_lds16((const char*)(Abase + row * 512 + kt) + cb,
                    (char*)As[nxt] + row * 64 + cb);
      }
#pragma unroll
      for (int j = 0; j < 2; ++j) {
        int row = j * 64 + r0;
        gload_lds16((const char*)(Bbase + row * 512 + kt) + cb,
                    (char*)Bs[nxt] + row * 64 + cb);
      }
      asm volatile("s_waitcnt vmcnt(8)" ::: "memory");
    } else if (t == 14) {
      asm volatile("s_waitcnt vmcnt(4)" ::: "memory");
    } else {
      asm volatile("s_waitcnt vmcnt(0)" ::: "memory");
    }
    __builtin_amdgcn_sched_barrier(0);
    __builtin_amdgcn_s_barrier();

    bf16x8 a[4], b[4];
#pragma unroll
    for (int mf = 0; mf < 4; ++mf)
      a[mf] = *(const bf16x8*)(As[cur] + (wr * 64 + mf * 16 + lrow) * 32 + kgrp * 8);
#pragma unroll
    for (int nf = 0; nf < 4; ++nf)
      b[nf] = *(const bf16x8*)(Bs[cur] + (wc * 64 + nf * 16 + lrow) * 32 + kgrp * 8);
    __builtin_amdgcn_s_setprio(1);
#pragma unroll
    for (int mf = 0; mf < 4; ++mf)
#pragma unroll
      for (int nf = 0; nf < 4; ++nf)
        acc[mf][nf] = __builtin_amdgcn_mfma_f32_16x16x32_bf16(a[mf], b[nf], acc[mf][nf], 0, 0, 0);
    __builtin_amdgcn_s_setprio(0);
  }
}

// ------- 128x256xK=512 NT-GEMM mainloop, TRIPLE-buffered, depth-2 (round-9) ------
__device__ __forceinline__ void gemm_nt_128x256_p3(const bf16_t* __restrict__ Abase,
                                                   const bf16_t* __restrict__ Bbase,
                                                   bf16_t (*As)[128 * 32],
                                                   bf16_t (*Bs)[256 * 32],
                                                   f32x4 acc[4][8]) {
  const int tid = threadIdx.x;
  const int lane = tid & 63;
  const int wid = tid >> 6;
  const int wr = wid >> 1, wc = wid & 1;
  const int lrow = lane & 15;
  const int kgrp = lane >> 4;
  const int r0 = tid >> 2;
  const int cb = (tid & 3) * 16;

#pragma unroll
  for (int p = 0; p < 2; ++p) {
    const int kt = p * 32;
#pragma unroll
    for (int j = 0; j < 2; ++j) {
      int row = j * 64 + r0;
      gload_lds16((const char*)(Abase + row * 512 + kt) + cb, (char*)As[p] + row * 64 + cb);
    }
#pragma unroll
    for (int j = 0; j < 4; ++j) {
      int row = j * 64 + r0;
      gload_lds16((const char*)(Bbase + row * 512 + kt) + cb, (char*)Bs[p] + row * 64 + cb);
    }
  }
  asm volatile("s_waitcnt vmcnt(6)" ::: "memory");
  __builtin_amdgcn_sched_barrier(0);

  int cur = 0, nxt = 2;
  for (int t = 0; t < 16; ++t) {
    __builtin_amdgcn_s_barrier();
    __builtin_amdgcn_sched_barrier(0);
    if (t < 14) {
      const int kt = (t + 2) * 32;
#pragma unroll
      for (int j = 0; j < 2; ++j) {
        int row = j * 64 + r0;
        gload_lds16((const char*)(Abase + row * 512 + kt) + cb,
                    (char*)As[nxt] + row * 64 + cb);
      }
#pragma unroll
      for (int j = 0; j < 4; ++j) {
        int row = j * 64 + r0;
        gload_lds16((const char*)(Bbase + row * 512 + kt) + cb,
                    (char*)Bs[nxt] + row * 64 + cb);
      }
    }

    bf16x8 a[4], b[8];
#pragma unroll
    for (int mf = 0; mf < 4; ++mf)
      a[mf] = *(const bf16x8*)(As[cur] + (wr * 64 + mf * 16 + lrow) * 32 + kgrp * 8);
#pragma unroll
    for (int nf = 0; nf < 8; ++nf)
      b[nf] = *(const bf16x8*)(Bs[cur] + (wc * 128 + nf * 16 + lrow) * 32 + kgrp * 8);
    __builtin_amdgcn_s_setprio(1);
#pragma unroll
    for (int mf = 0; mf < 4; ++mf)
#pragma unroll
      for (int nf = 0; nf < 8; ++nf)
        acc[mf][nf] = __builtin_amdgcn_mfma_f32_16x16x32_bf16(a[mf], b[nf], acc[mf][nf], 0, 0, 0);
    __builtin_amdgcn_s_setprio(0);
    if (t < 14) {
      asm volatile("s_waitcnt vmcnt(6)" ::: "memory");
    } else {
      asm volatile("s_waitcnt vmcnt(0)" ::: "memory");
    }
    __builtin_amdgcn_sched_barrier(0);
    cur = (cur == 2) ? 0 : cur + 1;
    nxt = (nxt == 2) ? 0 : nxt + 1;
  }
}

// ---------------- QKV projection: 128x256 tiles (round-9) ----------------
__global__ void __launch_bounds__(256, 2) gemm_qkv_kernel(
    const bf16_t* __restrict__ xr, const bf16_t* __restrict__ wT /* [1536][512] */,
    const float* __restrict__ bq, const float* __restrict__ bk,
    const float* __restrict__ bv, bf16_t* __restrict__ qo, bf16_t* __restrict__ ko,
    bf16_t* __restrict__ vto) {
  __shared__ bf16_t As[3][128 * 32];
  __shared__ bf16_t Bs[3][256 * 32];
  const int bn = blockIdx.x, bm = blockIdx.y;
  const int z = bn >> 1;
  const float* bias = (z == 0) ? bq : (z == 1) ? bk : bv;
  f32x4 acc[4][8] = {};
  gemm_nt_128x256_p3(xr + bm * 128 * 512, wT + (size_t)bn * 256 * 512, As, Bs, acc);
  const int lane = threadIdx.x & 63, wid = threadIdx.x >> 6;
  const int lrow = lane & 15, kgrp = lane >> 4;
  const int wr = wid >> 1, wc = wid & 1;
  const int row0 = bm * 128 + wr * 64;
  const int col0 = bn * 256 + wc * 128;
  const float qscale = 0.044194173824159216f * 1.4426950408889634f;
  if (z == 2) {
#pragma unroll
    for (int mf = 0; mf < 4; ++mf)
#pragma unroll
      for (int nf = 0; nf < 8; ++nf) {
        int nl = (col0 + nf * 16 + lrow) & 511;
        int h = nl >> 6, d = nl & 63;
        float bb = bias[nl];
        int m0 = row0 + mf * 16 + kgrp * 4;
        int b = m0 >> 10, s = m0 & 1023;
        bf16x4 pk;
#pragma unroll
        for (int r = 0; r < 4; ++r) pk[r] = (bf16_t)(acc[mf][nf][r] + bb);
        *(bf16x4*)(vto + (((size_t)(b * 8 + h) * 64 + d) * 1024 + s)) = pk;
      }
  } else {
    bf16_t* out = (z == 0) ? qo : ko;
    const float sc = (z == 0) ? qscale : 1.0f;
#pragma unroll
    for (int mf = 0; mf < 4; ++mf)
#pragma unroll
      for (int nf = 0; nf < 8; ++nf) {
        int nl = (col0 + nf * 16 + lrow) & 511;
        int h = nl >> 6, d = nl & 63;
        float bb = bias[nl];
#pragma unroll
        for (int r = 0; r < 4; ++r) {
          int m = row0 + mf * 16 + kgrp * 4 + r;
          int b = m >> 10, s = m & 1023;
          out[((b * 8 + h) * 1024 + s) * 64 + d] = (bf16_t)((acc[mf][nf][r] + bb) * sc);
        }
      }
  }
}

// ---------------- flash attention: 8 waves/block, 256 q rows, shared K/V tiles -----
// 3-buffer depth-2, barrier-first phase: {barrier; issue t+2; compute t; vmcnt}.
// Per staged 64-key tile: 2 gload_lds/thread (512 thr), serving all 8 waves.
__global__ void __launch_bounds__(512, 1) attn_kernel(const bf16_t* __restrict__ q,
                                                      const bf16_t* __restrict__ k,
                                                      const bf16_t* __restrict__ vt,
                                                      bf16_t* __restrict__ attn_out) {
  __shared__ char Ks[3][8192];   // [64 key][64 d] bf16, 128B rows, swizzled chunks
  __shared__ char Vs[3][8192];   // [64 d][64 key] bf16, swizzled
  __shared__ char Ps[8][4096];   // per-wave P [32 q][64 key] bf16, swizzled
  const int tid = threadIdx.x;
  const int lane = tid & 63, wid = tid >> 6;      // wid 0..7
  const int lrow = lane & 15, kgrp = lane >> 4;
  const int bh = blockIdx.x, qb = blockIdx.y;     // qb 0..3
  const int b = bh >> 3, h = bh & 7;

  const char* khb = (const char*)(k + (size_t)bh * 1024 * 64);
  const char* vthb = (const char*)(vt + (size_t)bh * 64 * 1024);
  const bf16_t* qh = q + (size_t)bh * 1024 * 64;

  const int qbase = qb * 256 + wid * 32;
  bf16x8 qa[2][2];
#pragma unroll
  for (int qf = 0; qf < 2; ++qf) {
    int qrow = qbase + qf * 16 + lrow;
    qa[qf][0] = *(const bf16x8*)(qh + qrow * 64 + kgrp * 8);
    qa[qf][1] = *(const bf16x8*)(qh + qrow * 64 + 32 + kgrp * 8);
  }

  char* Pw = Ps[wid];
  const int srow = tid >> 3;   // 0..63 (full tile row per pass)
  const int sc2 = tid & 7;

  float l_part[2] = {0.f, 0.f};
  f32x4 o[2][4] = {};

  // prologue: stage tiles 0,1 (K+V = 2 loads/thread per tile)
#pragma unroll
  for (int p = 0; p < 2; ++p) {
    gload_lds16(khb + p * 8192 + srow * 128 + ((sc2 ^ (srow & 7)) * 16),
                Ks[p] + tid * 16);
    gload_lds16(vthb + p * 128 + srow * 2048 + ((sc2 ^ (srow & 7)) * 16),
                Vs[p] + tid * 16);
  }
  asm volatile("s_waitcnt vmcnt(2)" ::: "memory");  // own tile-0 loads landed
  __builtin_amdgcn_sched_barrier(0);

  int cur = 0, nxt = 2;
  for (int t = 0; t < 16; ++t) {
    __builtin_amdgcn_s_barrier();
    __builtin_amdgcn_sched_barrier(0);
    if (t < 14) {
      gload_lds16(khb + (t + 2) * 8192 + srow * 128 + ((sc2 ^ (srow & 7)) * 16),
                  Ks[nxt] + tid * 16);
      gload_lds16(vthb + (t + 2) * 128 + srow * 2048 + ((sc2 ^ (srow & 7)) * 16),
                  Vs[nxt] + tid * 16);
    }

    const char* Kc = Ks[cur];
    const char* Vc = Vs[cur];

    // QK^T (swapped): sa[qf][c] col(lane&15)=q-within-16, row(kgrp*4+r)=key
    f32x4 sa[2][4] = {};
    __builtin_amdgcn_s_setprio(1);
#pragma unroll
    for (int c = 0; c < 4; ++c) {
      int krow = c * 16 + lrow;
      bf16x8 k0 = *(const bf16x8*)(Kc + krow * 128 + ((kgrp ^ (krow & 7)) * 16));
      bf16x8 k1 = *(const bf16x8*)(Kc + krow * 128 + (((4 + kgrp) ^ (krow & 7)) * 16));
#pragma unroll
      for (int qf = 0; qf < 2; ++qf) {
        sa[qf][c] = __builtin_amdgcn_mfma_f32_16x16x32_bf16(k0, qa[qf][0], sa[qf][c], 0, 0, 0);
        sa[qf][c] = __builtin_amdgcn_mfma_f32_16x16x32_bf16(k1, qa[qf][1], sa[qf][c], 0, 0, 0);
      }
    }
    __builtin_amdgcn_s_setprio(0);

    // softmax numerator + P store
#pragma unroll
    for (int qf = 0; qf < 2; ++qf) {
      int prow = qf * 16 + lrow;
      float rs = 0.f;
#pragma unroll
      for (int c = 0; c < 4; ++c) {
        bf16x4 pk;
#pragma unroll
        for (int r = 0; r < 4; ++r) {
          float p = exp2f(sa[qf][c][r]);
          rs += p;
          pk[r] = (bf16_t)p;
        }
        int chunk = (c * 2 + (kgrp >> 1)) ^ (prow & 7);
        *(bf16x4*)(Pw + prow * 128 + chunk * 16 + (kgrp & 1) * 8) = pk;
      }
      l_part[qf] += rs;
    }

    // PV
    __builtin_amdgcn_s_setprio(1);
#pragma unroll
    for (int kk = 0; kk < 2; ++kk) {
      bf16x8 pa[2];
#pragma unroll
      for (int qf = 0; qf < 2; ++qf) {
        int prow = qf * 16 + lrow;
        int pchunk = (kk * 4 + kgrp) ^ (prow & 7);
        pa[qf] = *(const bf16x8*)(Pw + prow * 128 + pchunk * 16);
      }
#pragma unroll
      for (int nfo = 0; nfo < 4; ++nfo) {
        int vrow = nfo * 16 + lrow;
        int vchunk = (kk * 4 + kgrp) ^ (vrow & 7);
        bf16x8 vb = *(const bf16x8*)(Vc + vrow * 128 + vchunk * 16);
#pragma unroll
        for (int qf = 0; qf < 2; ++qf)
          o[qf][nfo] = __builtin_amdgcn_mfma_f32_16x16x32_bf16(pa[qf], vb, o[qf][nfo], 0, 0, 0);
      }
    }
    __builtin_amdgcn_s_setprio(0);

    if (t < 14) {
      asm volatile("s_waitcnt vmcnt(2)" ::: "memory");  // tile t+1 landed
    } else {
      asm volatile("s_waitcnt vmcnt(0)" ::: "memory");
    }
    __builtin_amdgcn_sched_barrier(0);
    cur = (cur == 2) ? 0 : cur + 1;
    nxt = (nxt == 2) ? 0 : nxt + 1;
  }

  // epilogue
#pragma unroll
  for (int qf = 0; qf < 2; ++qf) {
    l_part[qf] += __shfl_xor(l_part[qf], 16, 64);
    l_part[qf] += __shfl_xor(l_part[qf], 32, 64);
  }
#pragma unroll
  for (int qf = 0; qf < 2; ++qf)
#pragma unroll
    for (int r = 0; r < 4; ++r) {
      float inv = 1.0f / __shfl(l_part[qf], kgrp * 4 + r, 64);
      int s = qbase + qf * 16 + kgrp * 4 + r;
#pragma unroll
      for (int nfo = 0; nfo < 4; ++nfo) {
        int d = nfo * 16 + lrow;
        attn_out[((b * 1024 + s) * 8 + h) * 64 + d] = (bf16_t)(o[qf][nfo][r] * inv);
      }
    }
}

// ---------------- out-proj (transposed): woT x attn + x -> out ----------------
__global__ void __launch_bounds__(256, 2) gemm_out_kernel(const bf16_t* __restrict__ woT,
                                                          const bf16_t* __restrict__ attn,
                                                          const float* __restrict__ x,
                                                          const float* __restrict__ bo,
                                                          float* __restrict__ out) {
  __shared__ bf16_t As[4][128 * 32];
  __shared__ bf16_t Bs[4][128 * 32];
  const int bn = blockIdx.x, bm = blockIdx.y;
  f32x4 acc[4][4] = {};
  gemm_nt_128x128_p4(woT + bm * 128 * 512, attn + bn * 128 * 512, As, Bs, acc);
  const int lane = threadIdx.x & 63, wid = threadIdx.x >> 6;
  const int wr = wid >> 1, wc = wid & 1;
  const int c0 = bm * 128 + wr * 64;
  const int s0g = bn * 128 + wc * 64;
#pragma unroll
  for (int mf = 0; mf < 4; ++mf)
#pragma unroll
    for (int r = 0; r < 4; ++r) {
      int c = c0 + mf * 16 + (lane >> 4) * 4 + r;
      float bias = bo[c];
#pragma unroll
      for (int nf = 0; nf < 4; ++nf) {
        int n = s0g + nf * 16 + (lane & 15);
        int b = n >> 10, s = n & 1023;
        int idx = (b * 512 + c) * 1024 + s;
        out[idx] = x[idx] + acc[mf][nf][r] + bias;
      }
    }
}

extern "C" void kernel_launch(void* const* d_in, const int* in_sizes, int n_in,
                              void* d_out, int out_size, void* d_ws, size_t ws_size,
                              hipStream_t stream) {
  const float* x  = (const float*)d_in[0];
  const float* wq = (const float*)d_in[1];
  const float* bq = (const float*)d_in[2];
  const float* wk = (const float*)d_in[3];
  const float* bk = (const float*)d_in[4];
  const float* wv = (const float*)d_in[5];
  const float* bv = (const float*)d_in[6];
  const float* wo = (const float*)d_in[7];
  const float* bo = (const float*)d_in[8];
  float* out = (float*)d_out;

  char* ws = (char*)d_ws;
  const size_t SZ_XR = (size_t)8192 * 512 * 2;         // 8 MB
  const size_t SZ_W  = (size_t)512 * 512 * 2;          // 0.5 MB
  const size_t SZ_T  = (size_t)8 * 8 * 1024 * 64 * 2;  // 8 MB
  bf16_t* xr   = (bf16_t*)(ws);
  bf16_t* wqT  = (bf16_t*)(ws + SZ_XR);                // wq/wk/wv contiguous [1536][512]
  bf16_t* wkT  = (bf16_t*)(ws + SZ_XR + SZ_W);
  bf16_t* wvT  = (bf16_t*)(ws + SZ_XR + 2 * SZ_W);
  bf16_t* woT  = (bf16_t*)(ws + SZ_XR + 3 * SZ_W);
  bf16_t* qd   = (bf16_t*)(ws + SZ_XR + 4 * SZ_W);
  bf16_t* kd   = (bf16_t*)(ws + SZ_XR + 4 * SZ_W + SZ_T);
  bf16_t* vtd  = (bf16_t*)(ws + SZ_XR + 4 * SZ_W + 2 * SZ_T);
  bf16_t* attn = (bf16_t*)(ws);                        // alias xr (dead by attn time)

  prep_kernel<<<dim3(1280), 256, 0, stream>>>(x, wq, wk, wv, wo, xr, wqT, wkT, wvT, woT);
  gemm_qkv_kernel<<<dim3(6, 64), 256, 0, stream>>>(xr, wqT, bq, bk, bv, qd, kd, vtd);
  attn_kernel<<<dim3(64, 4), 512, 0, stream>>>(qd, kd, vtd, attn);
  gemm_out_kernel<<<dim3(64, 4), 256, 0, stream>>>(woT, attn, x, bo, out);
}

// Round 11
// 84.413 us; speedup vs baseline: 1.0254x; 1.0254x over previous
//
#include <hip/hip_runtime.h>
#include <hip/hip_bf16.h>

typedef __bf16 bf16_t;
typedef __attribute__((ext_vector_type(8))) __bf16 bf16x8;
typedef __attribute__((ext_vector_type(4))) __bf16 bf16x4;
typedef __attribute__((ext_vector_type(4))) float f32x4;

#define AS1 __attribute__((address_space(1)))
#define AS3 __attribute__((address_space(3)))

__device__ __forceinline__ void gload_lds16(const void* g, void* l) {
  __builtin_amdgcn_global_load_lds((const AS1 void*)g, (AS3 void*)l, 16, 0, 0);
}

// ---------------- prep: vectorized transposes, 64x64 tiles (round-10) ----------------
__global__ void __launch_bounds__(256) prep_kernel(
    const float* __restrict__ x, const float* __restrict__ w0,
    const float* __restrict__ w1, const float* __restrict__ w2,
    const float* __restrict__ w3, bf16_t* __restrict__ xr, bf16_t* __restrict__ t0,
    bf16_t* __restrict__ t1, bf16_t* __restrict__ t2, bf16_t* __restrict__ t3) {
  __shared__ float tile[64][69];
  int t = blockIdx.x;
  const float* src;
  bf16_t* dst;
  int ld_src, ld_dst, R0, C0;
  if (t < 256) {
    int z = t >> 6, rem = t & 63;
    src = (z == 0) ? w0 : (z == 1) ? w1 : (z == 2) ? w2 : w3;
    dst = (z == 0) ? t0 : (z == 1) ? t1 : (z == 2) ? t2 : t3;
    ld_src = 512; ld_dst = 512;
    R0 = (rem >> 3) * 64;
    C0 = (rem & 7) * 64;
  } else {
    t -= 256;
    int b = t >> 7, rem = t & 127;
    src = x + (size_t)b * 512 * 1024;
    dst = xr + (size_t)b * 1024 * 512;
    ld_src = 1024; ld_dst = 512;
    R0 = (rem >> 4) * 64;
    C0 = (rem & 15) * 64;
  }
  const int tid = threadIdx.x;
  const int rl = tid >> 4;
  const int cl = (tid & 15) * 4;
#pragma unroll
  for (int p = 0; p < 4; ++p) {
    int r = p * 16 + rl;
    float4 v = *(const float4*)(src + (size_t)(R0 + r) * ld_src + C0 + cl);
    tile[r][cl + 0] = v.x;
    tile[r][cl + 1] = v.y;
    tile[r][cl + 2] = v.z;
    tile[r][cl + 3] = v.w;
  }
  __syncthreads();
  const int kk = tid & 7;
  const int cw = tid >> 3;
#pragma unroll
  for (int p = 0; p < 2; ++p) {
    int c = p * 32 + cw;
    bf16x8 o;
#pragma unroll
    for (int j = 0; j < 8; ++j) o[j] = (bf16_t)tile[kk * 8 + j][c];
    *(bf16x8*)(dst + (size_t)(C0 + c) * ld_dst + R0 + kk * 8) = o;
  }
}

// ------- 128x128xK=512 NT-GEMM mainloop, QUAD-buffered, depth-2 (round-7) -------
__device__ __forceinline__ void gemm_nt_128x128_p4(const bf16_t* __restrict__ Abase,
                                                   const bf16_t* __restrict__ Bbase,
                                                   bf16_t (*As)[128 * 32],
                                                   bf16_t (*Bs)[128 * 32],
                                                   f32x4 acc[4][4]) {
  const int tid = threadIdx.x;
  const int lane = tid & 63;
  const int wid = tid >> 6;
  const int wr = wid >> 1, wc = wid & 1;
  const int lrow = lane & 15;
  const int kgrp = lane >> 4;
  const int r0 = tid >> 2;
  const int cb = (tid & 3) * 16;

#pragma unroll
  for (int p = 0; p < 2; ++p) {
    const int kt = p * 32;
#pragma unroll
    for (int j = 0; j < 2; ++j) {
      int row = j * 64 + r0;
      gload_lds16((const char*)(Abase + row * 512 + kt) + cb, (char*)As[p] + row * 64 + cb);
    }
#pragma unroll
    for (int j = 0; j < 2; ++j) {
      int row = j * 64 + r0;
      gload_lds16((const char*)(Bbase + row * 512 + kt) + cb, (char*)Bs[p] + row * 64 + cb);
    }
  }

  for (int t = 0; t < 16; ++t) {
    const int cur = t & 3;
    if (t < 14) {
      const int nxt = (t + 2) & 3;
      const int kt = (t + 2) * 32;
#pragma unroll
      for (int j = 0; j < 2; ++j) {
        int row = j * 64 + r0;
        gload_lds16((const char*)(Abase + row * 512 + kt) + cb,
                    (char*)As[nxt] + row * 64 + cb);
      }
#pragma unroll
      for (int j = 0; j < 2; ++j) {
        int row = j * 64 + r0;
        gload_lds16((const char*)(Bbase + row * 512 + kt) + cb,
                    (char*)Bs[nxt] + row * 64 + cb);
      }
      asm volatile("s_waitcnt vmcnt(8)" ::: "memory");
    } else if (t == 14) {
      asm volatile("s_waitcnt vmcnt(4)" ::: "memory");
    } else {
      asm volatile("s_waitcnt vmcnt(0)" ::: "memory");
    }
    __builtin_amdgcn_sched_barrier(0);
    __builtin_amdgcn_s_barrier();

    bf16x8 a[4], b[4];
#pragma unroll
    for (int mf = 0; mf < 4; ++mf)
      a[mf] = *(const bf16x8*)(As[cur] + (wr * 64 + mf * 16 + lrow) * 32 + kgrp * 8);
#pragma unroll
    for (int nf = 0; nf < 4; ++nf)
      b[nf] = *(const bf16x8*)(Bs[cur] + (wc * 64 + nf * 16 + lrow) * 32 + kgrp * 8);
    __builtin_amdgcn_s_setprio(1);
#pragma unroll
    for (int mf = 0; mf < 4; ++mf)
#pragma unroll
      for (int nf = 0; nf < 4; ++nf)
        acc[mf][nf] = __builtin_amdgcn_mfma_f32_16x16x32_bf16(a[mf], b[nf], acc[mf][nf], 0, 0, 0);
    __builtin_amdgcn_s_setprio(0);
  }
}

// ------- 128x256xK=512 NT-GEMM mainloop, TRIPLE-buffered, depth-2 (round-9) ------
__device__ __forceinline__ void gemm_nt_128x256_p3(const bf16_t* __restrict__ Abase,
                                                   const bf16_t* __restrict__ Bbase,
                                                   bf16_t (*As)[128 * 32],
                                                   bf16_t (*Bs)[256 * 32],
                                                   f32x4 acc[4][8]) {
  const int tid = threadIdx.x;
  const int lane = tid & 63;
  const int wid = tid >> 6;
  const int wr = wid >> 1, wc = wid & 1;
  const int lrow = lane & 15;
  const int kgrp = lane >> 4;
  const int r0 = tid >> 2;
  const int cb = (tid & 3) * 16;

#pragma unroll
  for (int p = 0; p < 2; ++p) {
    const int kt = p * 32;
#pragma unroll
    for (int j = 0; j < 2; ++j) {
      int row = j * 64 + r0;
      gload_lds16((const char*)(Abase + row * 512 + kt) + cb, (char*)As[p] + row * 64 + cb);
    }
#pragma unroll
    for (int j = 0; j < 4; ++j) {
      int row = j * 64 + r0;
      gload_lds16((const char*)(Bbase + row * 512 + kt) + cb, (char*)Bs[p] + row * 64 + cb);
    }
  }
  asm volatile("s_waitcnt vmcnt(6)" ::: "memory");
  __builtin_amdgcn_sched_barrier(0);

  int cur = 0, nxt = 2;
  for (int t = 0; t < 16; ++t) {
    __builtin_amdgcn_s_barrier();
    __builtin_amdgcn_sched_barrier(0);
    if (t < 14) {
      const int kt = (t + 2) * 32;
#pragma unroll
      for (int j = 0; j < 2; ++j) {
        int row = j * 64 + r0;
        gload_lds16((const char*)(Abase + row * 512 + kt) + cb,
                    (char*)As[nxt] + row * 64 + cb);
      }
#pragma unroll
      for (int j = 0; j < 4; ++j) {
        int row = j * 64 + r0;
        gload_lds16((const char*)(Bbase + row * 512 + kt) + cb,
                    (char*)Bs[nxt] + row * 64 + cb);
      }
    }

    bf16x8 a[4], b[8];
#pragma unroll
    for (int mf = 0; mf < 4; ++mf)
      a[mf] = *(const bf16x8*)(As[cur] + (wr * 64 + mf * 16 + lrow) * 32 + kgrp * 8);
#pragma unroll
    for (int nf = 0; nf < 8; ++nf)
      b[nf] = *(const bf16x8*)(Bs[cur] + (wc * 128 + nf * 16 + lrow) * 32 + kgrp * 8);
    __builtin_amdgcn_s_setprio(1);
#pragma unroll
    for (int mf = 0; mf < 4; ++mf)
#pragma unroll
      for (int nf = 0; nf < 8; ++nf)
        acc[mf][nf] = __builtin_amdgcn_mfma_f32_16x16x32_bf16(a[mf], b[nf], acc[mf][nf], 0, 0, 0);
    __builtin_amdgcn_s_setprio(0);
    if (t < 14) {
      asm volatile("s_waitcnt vmcnt(6)" ::: "memory");
    } else {
      asm volatile("s_waitcnt vmcnt(0)" ::: "memory");
    }
    __builtin_amdgcn_sched_barrier(0);
    cur = (cur == 2) ? 0 : cur + 1;
    nxt = (nxt == 2) ? 0 : nxt + 1;
  }
}

// ---------------- QKV projection: 128x256 tiles (round-9) ----------------
__global__ void __launch_bounds__(256, 2) gemm_qkv_kernel(
    const bf16_t* __restrict__ xr, const bf16_t* __restrict__ wT /* [1536][512] */,
    const float* __restrict__ bq, const float* __restrict__ bk,
    const float* __restrict__ bv, bf16_t* __restrict__ qo, bf16_t* __restrict__ ko,
    bf16_t* __restrict__ vto) {
  __shared__ bf16_t As[3][128 * 32];
  __shared__ bf16_t Bs[3][256 * 32];
  const int bn = blockIdx.x, bm = blockIdx.y;
  const int z = bn >> 1;
  const float* bias = (z == 0) ? bq : (z == 1) ? bk : bv;
  f32x4 acc[4][8] = {};
  gemm_nt_128x256_p3(xr + bm * 128 * 512, wT + (size_t)bn * 256 * 512, As, Bs, acc);
  const int lane = threadIdx.x & 63, wid = threadIdx.x >> 6;
  const int lrow = lane & 15, kgrp = lane >> 4;
  const int wr = wid >> 1, wc = wid & 1;
  const int row0 = bm * 128 + wr * 64;
  const int col0 = bn * 256 + wc * 128;
  const float qscale = 0.044194173824159216f * 1.4426950408889634f;
  if (z == 2) {
#pragma unroll
    for (int mf = 0; mf < 4; ++mf)
#pragma unroll
      for (int nf = 0; nf < 8; ++nf) {
        int nl = (col0 + nf * 16 + lrow) & 511;
        int h = nl >> 6, d = nl & 63;
        float bb = bias[nl];
        int m0 = row0 + mf * 16 + kgrp * 4;
        int b = m0 >> 10, s = m0 & 1023;
        bf16x4 pk;
#pragma unroll
        for (int r = 0; r < 4; ++r) pk[r] = (bf16_t)(acc[mf][nf][r] + bb);
        *(bf16x4*)(vto + (((size_t)(b * 8 + h) * 64 + d) * 1024 + s)) = pk;
      }
  } else {
    bf16_t* out = (z == 0) ? qo : ko;
    const float sc = (z == 0) ? qscale : 1.0f;
#pragma unroll
    for (int mf = 0; mf < 4; ++mf)
#pragma unroll
      for (int nf = 0; nf < 8; ++nf) {
        int nl = (col0 + nf * 16 + lrow) & 511;
        int h = nl >> 6, d = nl & 63;
        float bb = bias[nl];
#pragma unroll
        for (int r = 0; r < 4; ++r) {
          int m = row0 + mf * 16 + kgrp * 4 + r;
          int b = m >> 10, s = m & 1023;
          out[((b * 8 + h) * 1024 + s) * 64 + d] = (bf16_t)((acc[mf][nf][r] + bb) * sc);
        }
      }
  }
}

// ---------------- flash attention (round-7): 4 waves, quad-buffered, depth-2 ------
__global__ void __launch_bounds__(256, 2) attn_kernel(const bf16_t* __restrict__ q,
                                                      const bf16_t* __restrict__ k,
                                                      const bf16_t* __restrict__ vt,
                                                      bf16_t* __restrict__ attn_out) {
  __shared__ char Ks[4][8192];   // [64 key][64 d] bf16, 128B rows, 16B-chunk swizzled
  __shared__ char Vs[4][8192];   // [64 d][64 key] bf16, 128B rows, swizzled
  __shared__ char Ps[4][4096];   // per-wave P [32 q][64 key] bf16, swizzled
  const int tid = threadIdx.x;
  const int lane = tid & 63, wid = tid >> 6;
  const int lrow = lane & 15, kgrp = lane >> 4;
  const int bh = blockIdx.x, qb = blockIdx.y;
  const int b = bh >> 3, h = bh & 7;

  const char* khb = (const char*)(k + (size_t)bh * 1024 * 64);
  const char* vthb = (const char*)(vt + (size_t)bh * 64 * 1024);
  const bf16_t* qh = q + (size_t)bh * 1024 * 64;

  const int qbase = qb * 128 + wid * 32;
  bf16x8 qa[2][2];
#pragma unroll
  for (int qf = 0; qf < 2; ++qf) {
    int qrow = qbase + qf * 16 + lrow;
    qa[qf][0] = *(const bf16x8*)(qh + qrow * 64 + kgrp * 8);
    qa[qf][1] = *(const bf16x8*)(qh + qrow * 64 + 32 + kgrp * 8);
  }

  char* Pw = Ps[wid];
  const int srow = tid >> 3;
  const int sc2 = tid & 7;

  float l_part[2] = {0.f, 0.f};
  f32x4 o[2][4] = {};

#pragma unroll
  for (int p = 0; p < 2; ++p) {
    const char* kg = khb + p * (64 * 128);
    const char* vg = vthb + p * 128;
#pragma unroll
    for (int j = 0; j < 2; ++j) {
      int row = j * 32 + srow;
      gload_lds16(kg + row * 128 + ((sc2 ^ (row & 7)) * 16), Ks[p] + j * 4096 + tid * 16);
    }
#pragma unroll
    for (int j = 0; j < 2; ++j) {
      int row = j * 32 + srow;
      gload_lds16(vg + row * 2048 + ((sc2 ^ (row & 7)) * 16), Vs[p] + j * 4096 + tid * 16);
    }
  }

  for (int t = 0; t < 16; ++t) {
    const int cur = t & 3;
    if (t < 14) {
      const int nxt = (t + 2) & 3;
      const char* kg = khb + (t + 2) * (64 * 128);
      const char* vg = vthb + (t + 2) * 128;
#pragma unroll
      for (int j = 0; j < 2; ++j) {
        int row = j * 32 + srow;
        gload_lds16(kg + row * 128 + ((sc2 ^ (row & 7)) * 16),
                    Ks[nxt] + j * 4096 + tid * 16);
      }
#pragma unroll
      for (int j = 0; j < 2; ++j) {
        int row = j * 32 + srow;
        gload_lds16(vg + row * 2048 + ((sc2 ^ (row & 7)) * 16),
                    Vs[nxt] + j * 4096 + tid * 16);
      }
      asm volatile("s_waitcnt vmcnt(8)" ::: "memory");
    } else if (t == 14) {
      asm volatile("s_waitcnt vmcnt(4)" ::: "memory");
    } else {
      asm volatile("s_waitcnt vmcnt(0)" ::: "memory");
    }
    __builtin_amdgcn_sched_barrier(0);
    __builtin_amdgcn_s_barrier();

    const char* Kc = Ks[cur];
    const char* Vc = Vs[cur];

    f32x4 sa[2][4] = {};
    __builtin_amdgcn_s_setprio(1);
#pragma unroll
    for (int c = 0; c < 4; ++c) {
      int krow = c * 16 + lrow;
      bf16x8 k0 = *(const bf16x8*)(Kc + krow * 128 + ((kgrp ^ (krow & 7)) * 16));
      bf16x8 k1 = *(const bf16x8*)(Kc + krow * 128 + (((4 + kgrp) ^ (krow & 7)) * 16));
#pragma unroll
      for (int qf = 0; qf < 2; ++qf) {
        sa[qf][c] = __builtin_amdgcn_mfma_f32_16x16x32_bf16(k0, qa[qf][0], sa[qf][c], 0, 0, 0);
        sa[qf][c] = __builtin_amdgcn_mfma_f32_16x16x32_bf16(k1, qa[qf][1], sa[qf][c], 0, 0, 0);
      }
    }
    __builtin_amdgcn_s_setprio(0);

#pragma unroll
    for (int qf = 0; qf < 2; ++qf) {
      int prow = qf * 16 + lrow;
      float rs = 0.f;
#pragma unroll
      for (int c = 0; c < 4; ++c) {
        bf16x4 pk;
#pragma unroll
        for (int r = 0; r < 4; ++r) {
          float p = exp2f(sa[qf][c][r]);
          rs += p;
          pk[r] = (bf16_t)p;
        }
        int chunk = (c * 2 + (kgrp >> 1)) ^ (prow & 7);
        *(bf16x4*)(Pw + prow * 128 + chunk * 16 + (kgrp & 1) * 8) = pk;
      }
      l_part[qf] += rs;
    }

    __builtin_amdgcn_s_setprio(1);
#pragma unroll
    for (int kk = 0; kk < 2; ++kk) {
      bf16x8 pa[2];
#pragma unroll
      for (int qf = 0; qf < 2; ++qf) {
        int prow = qf * 16 + lrow;
        int pchunk = (kk * 4 + kgrp) ^ (prow & 7);
        pa[qf] = *(const bf16x8*)(Pw + prow * 128 + pchunk * 16);
      }
#pragma unroll
      for (int nfo = 0; nfo < 4; ++nfo) {
        int vrow = nfo * 16 + lrow;
        int vchunk = (kk * 4 + kgrp) ^ (vrow & 7);
        bf16x8 vb = *(const bf16x8*)(Vc + vrow * 128 + vchunk * 16);
#pragma unroll
        for (int qf = 0; qf < 2; ++qf)
          o[qf][nfo] = __builtin_amdgcn_mfma_f32_16x16x32_bf16(pa[qf], vb, o[qf][nfo], 0, 0, 0);
      }
    }
    __builtin_amdgcn_s_setprio(0);
  }

#pragma unroll
  for (int qf = 0; qf < 2; ++qf) {
    l_part[qf] += __shfl_xor(l_part[qf], 16, 64);
    l_part[qf] += __shfl_xor(l_part[qf], 32, 64);
  }
#pragma unroll
  for (int qf = 0; qf < 2; ++qf)
#pragma unroll
    for (int r = 0; r < 4; ++r) {
      float inv = 1.0f / __shfl(l_part[qf], kgrp * 4 + r, 64);
      int s = qbase + qf * 16 + kgrp * 4 + r;
#pragma unroll
      for (int nfo = 0; nfo < 4; ++nfo) {
        int d = nfo * 16 + lrow;
        attn_out[((b * 1024 + s) * 8 + h) * 64 + d] = (bf16_t)(o[qf][nfo][r] * inv);
      }
    }
}

// ---------------- out-proj (transposed): woT x attn + x -> out ----------------
__global__ void __launch_bounds__(256, 2) gemm_out_kernel(const bf16_t* __restrict__ woT,
                                                          const bf16_t* __restrict__ attn,
                                                          const float* __restrict__ x,
                                                          const float* __restrict__ bo,
                                                          float* __restrict__ out) {
  __shared__ bf16_t As[4][128 * 32];
  __shared__ bf16_t Bs[4][128 * 32];
  const int bn = blockIdx.x, bm = blockIdx.y;
  f32x4 acc[4][4] = {};
  gemm_nt_128x128_p4(woT + bm * 128 * 512, attn + bn * 128 * 512, As, Bs, acc);
  const int lane = threadIdx.x & 63, wid = threadIdx.x >> 6;
  const int wr = wid >> 1, wc = wid & 1;
  const int c0 = bm * 128 + wr * 64;
  const int s0g = bn * 128 + wc * 64;
#pragma unroll
  for (int mf = 0; mf < 4; ++mf)
#pragma unroll
    for (int r = 0; r < 4; ++r) {
      int c = c0 + mf * 16 + (lane >> 4) * 4 + r;
      float bias = bo[c];
#pragma unroll
      for (int nf = 0; nf < 4; ++nf) {
        int n = s0g + nf * 16 + (lane & 15);
        int b = n >> 10, s = n & 1023;
        int idx = (b * 512 + c) * 1024 + s;
        out[idx] = x[idx] + acc[mf][nf][r] + bias;
      }
    }
}

extern "C" void kernel_launch(void* const* d_in, const int* in_sizes, int n_in,
                              void* d_out, int out_size, void* d_ws, size_t ws_size,
                              hipStream_t stream) {
  const float* x  = (const float*)d_in[0];
  const float* wq = (const float*)d_in[1];
  const float* bq = (const float*)d_in[2];
  const float* wk = (const float*)d_in[3];
  const float* bk = (const float*)d_in[4];
  const float* wv = (const float*)d_in[5];
  const float* bv = (const float*)d_in[6];
  const float* wo = (const float*)d_in[7];
  const float* bo = (const float*)d_in[8];
  float* out = (float*)d_out;

  char* ws = (char*)d_ws;
  const size_t SZ_XR = (size_t)8192 * 512 * 2;         // 8 MB
  const size_t SZ_W  = (size_t)512 * 512 * 2;          // 0.5 MB
  const size_t SZ_T  = (size_t)8 * 8 * 1024 * 64 * 2;  // 8 MB
  bf16_t* xr   = (bf16_t*)(ws);
  bf16_t* wqT  = (bf16_t*)(ws + SZ_XR);                // wq/wk/wv contiguous [1536][512]
  bf16_t* wkT  = (bf16_t*)(ws + SZ_XR + SZ_W);
  bf16_t* wvT  = (bf16_t*)(ws + SZ_XR + 2 * SZ_W);
  bf16_t* woT  = (bf16_t*)(ws + SZ_XR + 3 * SZ_W);
  bf16_t* qd   = (bf16_t*)(ws + SZ_XR + 4 * SZ_W);
  bf16_t* kd   = (bf16_t*)(ws + SZ_XR + 4 * SZ_W + SZ_T);
  bf16_t* vtd  = (bf16_t*)(ws + SZ_XR + 4 * SZ_W + 2 * SZ_T);
  bf16_t* attn = (bf16_t*)(ws);                        // alias xr (dead by attn time)

  prep_kernel<<<dim3(1280), 256, 0, stream>>>(x, wq, wk, wv, wo, xr, wqT, wkT, wvT, woT);
  gemm_qkv_kernel<<<dim3(6, 64), 256, 0, stream>>>(xr, wqT, bq, bk, bv, qd, kd, vtd);
  attn_kernel<<<dim3(64, 8), 256, 0, stream>>>(qd, kd, vtd, attn);
  gemm_out_kernel<<<dim3(64, 4), 256, 0, stream>>>(woT, attn, x, bo, out);
}

// Round 12
// 81.885 us; speedup vs baseline: 1.0571x; 1.0309x over previous
//
#include <hip/hip_runtime.h>
#include <hip/hip_bf16.h>

typedef __bf16 bf16_t;
typedef __attribute__((ext_vector_type(8))) __bf16 bf16x8;
typedef __attribute__((ext_vector_type(4))) __bf16 bf16x4;
typedef __attribute__((ext_vector_type(4))) float f32x4;

#define AS1 __attribute__((address_space(1)))
#define AS3 __attribute__((address_space(3)))

__device__ __forceinline__ void gload_lds16(const void* g, void* l) {
  __builtin_amdgcn_global_load_lds((const AS1 void*)g, (AS3 void*)l, 16, 0, 0);
}

// ---------------- prep: vectorized transposes, 64x64 tiles (round-10) ----------------
__global__ void __launch_bounds__(256) prep_kernel(
    const float* __restrict__ x, const float* __restrict__ w0,
    const float* __restrict__ w1, const float* __restrict__ w2,
    const float* __restrict__ w3, bf16_t* __restrict__ xr, bf16_t* __restrict__ t0,
    bf16_t* __restrict__ t1, bf16_t* __restrict__ t2, bf16_t* __restrict__ t3) {
  __shared__ float tile[64][69];
  int t = blockIdx.x;
  const float* src;
  bf16_t* dst;
  int ld_src, ld_dst, R0, C0;
  if (t < 256) {
    int z = t >> 6, rem = t & 63;
    src = (z == 0) ? w0 : (z == 1) ? w1 : (z == 2) ? w2 : w3;
    dst = (z == 0) ? t0 : (z == 1) ? t1 : (z == 2) ? t2 : t3;
    ld_src = 512; ld_dst = 512;
    R0 = (rem >> 3) * 64;
    C0 = (rem & 7) * 64;
  } else {
    t -= 256;
    int b = t >> 7, rem = t & 127;
    src = x + (size_t)b * 512 * 1024;
    dst = xr + (size_t)b * 1024 * 512;
    ld_src = 1024; ld_dst = 512;
    R0 = (rem >> 4) * 64;
    C0 = (rem & 15) * 64;
  }
  const int tid = threadIdx.x;
  const int rl = tid >> 4;
  const int cl = (tid & 15) * 4;
#pragma unroll
  for (int p = 0; p < 4; ++p) {
    int r = p * 16 + rl;
    float4 v = *(const float4*)(src + (size_t)(R0 + r) * ld_src + C0 + cl);
    tile[r][cl + 0] = v.x;
    tile[r][cl + 1] = v.y;
    tile[r][cl + 2] = v.z;
    tile[r][cl + 3] = v.w;
  }
  __syncthreads();
  const int kk = tid & 7;
  const int cw = tid >> 3;
#pragma unroll
  for (int p = 0; p < 2; ++p) {
    int c = p * 32 + cw;
    bf16x8 o;
#pragma unroll
    for (int j = 0; j < 8; ++j) o[j] = (bf16_t)tile[kk * 8 + j][c];
    *(bf16x8*)(dst + (size_t)(C0 + c) * ld_dst + R0 + kk * 8) = o;
  }
}

// ------- 128x256xK=512 NT-GEMM mainloop, TRIPLE-buffered, depth-2 (round-9) ------
__device__ __forceinline__ void gemm_nt_128x256_p3(const bf16_t* __restrict__ Abase,
                                                   const bf16_t* __restrict__ Bbase,
                                                   bf16_t (*As)[128 * 32],
                                                   bf16_t (*Bs)[256 * 32],
                                                   f32x4 acc[4][8]) {
  const int tid = threadIdx.x;
  const int lane = tid & 63;
  const int wid = tid >> 6;
  const int wr = wid >> 1, wc = wid & 1;
  const int lrow = lane & 15;
  const int kgrp = lane >> 4;
  const int r0 = tid >> 2;
  const int cb = (tid & 3) * 16;

#pragma unroll
  for (int p = 0; p < 2; ++p) {
    const int kt = p * 32;
#pragma unroll
    for (int j = 0; j < 2; ++j) {
      int row = j * 64 + r0;
      gload_lds16((const char*)(Abase + row * 512 + kt) + cb, (char*)As[p] + row * 64 + cb);
    }
#pragma unroll
    for (int j = 0; j < 4; ++j) {
      int row = j * 64 + r0;
      gload_lds16((const char*)(Bbase + row * 512 + kt) + cb, (char*)Bs[p] + row * 64 + cb);
    }
  }
  asm volatile("s_waitcnt vmcnt(6)" ::: "memory");
  __builtin_amdgcn_sched_barrier(0);

  int cur = 0, nxt = 2;
  for (int t = 0; t < 16; ++t) {
    __builtin_amdgcn_s_barrier();
    __builtin_amdgcn_sched_barrier(0);
    if (t < 14) {
      const int kt = (t + 2) * 32;
#pragma unroll
      for (int j = 0; j < 2; ++j) {
        int row = j * 64 + r0;
        gload_lds16((const char*)(Abase + row * 512 + kt) + cb,
                    (char*)As[nxt] + row * 64 + cb);
      }
#pragma unroll
      for (int j = 0; j < 4; ++j) {
        int row = j * 64 + r0;
        gload_lds16((const char*)(Bbase + row * 512 + kt) + cb,
                    (char*)Bs[nxt] + row * 64 + cb);
      }
    }

    bf16x8 a[4], b[8];
#pragma unroll
    for (int mf = 0; mf < 4; ++mf)
      a[mf] = *(const bf16x8*)(As[cur] + (wr * 64 + mf * 16 + lrow) * 32 + kgrp * 8);
#pragma unroll
    for (int nf = 0; nf < 8; ++nf)
      b[nf] = *(const bf16x8*)(Bs[cur] + (wc * 128 + nf * 16 + lrow) * 32 + kgrp * 8);
    __builtin_amdgcn_s_setprio(1);
#pragma unroll
    for (int mf = 0; mf < 4; ++mf)
#pragma unroll
      for (int nf = 0; nf < 8; ++nf)
        acc[mf][nf] = __builtin_amdgcn_mfma_f32_16x16x32_bf16(a[mf], b[nf], acc[mf][nf], 0, 0, 0);
    __builtin_amdgcn_s_setprio(0);
    if (t < 14) {
      asm volatile("s_waitcnt vmcnt(6)" ::: "memory");
    } else {
      asm volatile("s_waitcnt vmcnt(0)" ::: "memory");
    }
    __builtin_amdgcn_sched_barrier(0);
    cur = (cur == 2) ? 0 : cur + 1;
    nxt = (nxt == 2) ? 0 : nxt + 1;
  }
}

// ---------------- QKV projection: 128x256 tiles (round-9) ----------------
__global__ void __launch_bounds__(256, 2) gemm_qkv_kernel(
    const bf16_t* __restrict__ xr, const bf16_t* __restrict__ wT /* [1536][512] */,
    const float* __restrict__ bq, const float* __restrict__ bk,
    const float* __restrict__ bv, bf16_t* __restrict__ qo, bf16_t* __restrict__ ko,
    bf16_t* __restrict__ vto) {
  __shared__ bf16_t As[3][128 * 32];
  __shared__ bf16_t Bs[3][256 * 32];
  const int bn = blockIdx.x, bm = blockIdx.y;
  const int z = bn >> 1;
  const float* bias = (z == 0) ? bq : (z == 1) ? bk : bv;
  f32x4 acc[4][8] = {};
  gemm_nt_128x256_p3(xr + bm * 128 * 512, wT + (size_t)bn * 256 * 512, As, Bs, acc);
  const int lane = threadIdx.x & 63, wid = threadIdx.x >> 6;
  const int lrow = lane & 15, kgrp = lane >> 4;
  const int wr = wid >> 1, wc = wid & 1;
  const int row0 = bm * 128 + wr * 64;
  const int col0 = bn * 256 + wc * 128;
  const float qscale = 0.044194173824159216f * 1.4426950408889634f;
  if (z == 2) {
#pragma unroll
    for (int mf = 0; mf < 4; ++mf)
#pragma unroll
      for (int nf = 0; nf < 8; ++nf) {
        int nl = (col0 + nf * 16 + lrow) & 511;
        int h = nl >> 6, d = nl & 63;
        float bb = bias[nl];
        int m0 = row0 + mf * 16 + kgrp * 4;
        int b = m0 >> 10, s = m0 & 1023;
        bf16x4 pk;
#pragma unroll
        for (int r = 0; r < 4; ++r) pk[r] = (bf16_t)(acc[mf][nf][r] + bb);
        *(bf16x4*)(vto + (((size_t)(b * 8 + h) * 64 + d) * 1024 + s)) = pk;
      }
  } else {
    bf16_t* out = (z == 0) ? qo : ko;
    const float sc = (z == 0) ? qscale : 1.0f;
#pragma unroll
    for (int mf = 0; mf < 4; ++mf)
#pragma unroll
      for (int nf = 0; nf < 8; ++nf) {
        int nl = (col0 + nf * 16 + lrow) & 511;
        int h = nl >> 6, d = nl & 63;
        float bb = bias[nl];
#pragma unroll
        for (int r = 0; r < 4; ++r) {
          int m = row0 + mf * 16 + kgrp * 4 + r;
          int b = m >> 10, s = m & 1023;
          out[((b * 8 + h) * 1024 + s) * 64 + d] = (bf16_t)((acc[mf][nf][r] + bb) * sc);
        }
      }
  }
}

// ---------------- flash attention: pair-merged phases (8 barriers), 4 waves -------
// Same 4 LDS buffers as r7; per phase: {barrier; issue pair T+1 -> disjoint bufs;
// vmcnt(8) [current pair landed]; compute old-tiles 2T and 2T+1}.
__global__ void __launch_bounds__(256, 2) attn_kernel(const bf16_t* __restrict__ q,
                                                      const bf16_t* __restrict__ k,
                                                      const bf16_t* __restrict__ vt,
                                                      bf16_t* __restrict__ attn_out) {
  __shared__ char Ks[4][8192];   // [64 key][64 d] bf16, 128B rows, 16B-chunk swizzled
  __shared__ char Vs[4][8192];   // [64 d][64 key] bf16, 128B rows, swizzled
  __shared__ char Ps[4][4096];   // per-wave P [32 q][64 key] bf16, swizzled
  const int tid = threadIdx.x;
  const int lane = tid & 63, wid = tid >> 6;
  const int lrow = lane & 15, kgrp = lane >> 4;
  const int bh = blockIdx.x, qb = blockIdx.y;
  const int b = bh >> 3, h = bh & 7;

  const char* khb = (const char*)(k + (size_t)bh * 1024 * 64);
  const char* vthb = (const char*)(vt + (size_t)bh * 64 * 1024);
  const bf16_t* qh = q + (size_t)bh * 1024 * 64;

  const int qbase = qb * 128 + wid * 32;
  bf16x8 qa[2][2];
#pragma unroll
  for (int qf = 0; qf < 2; ++qf) {
    int qrow = qbase + qf * 16 + lrow;
    qa[qf][0] = *(const bf16x8*)(qh + qrow * 64 + kgrp * 8);
    qa[qf][1] = *(const bf16x8*)(qh + qrow * 64 + 32 + kgrp * 8);
  }

  char* Pw = Ps[wid];
  const int srow = tid >> 3;
  const int sc2 = tid & 7;

  float l_part[2] = {0.f, 0.f};
  f32x4 o[2][4] = {};

  // prologue: issue old-tiles 0,1
#pragma unroll
  for (int p = 0; p < 2; ++p) {
    const char* kg = khb + p * 8192;
    const char* vg = vthb + p * 128;
#pragma unroll
    for (int j = 0; j < 2; ++j) {
      int row = j * 32 + srow;
      gload_lds16(kg + row * 128 + ((sc2 ^ (row & 7)) * 16), Ks[p] + j * 4096 + tid * 16);
    }
#pragma unroll
    for (int j = 0; j < 2; ++j) {
      int row = j * 32 + srow;
      gload_lds16(vg + row * 2048 + ((sc2 ^ (row & 7)) * 16), Vs[p] + j * 4096 + tid * 16);
    }
  }

  for (int T = 0; T < 8; ++T) {
    __builtin_amdgcn_s_barrier();
    __builtin_amdgcn_sched_barrier(0);
    if (T < 7) {
      // issue pair T+1 into the buffers NOT being computed this phase
#pragma unroll
      for (int p = 0; p < 2; ++p) {
        const int u = 2 * T + 2 + p;
        const int bu = u & 3;
        const char* kg = khb + u * 8192;
        const char* vg = vthb + u * 128;
#pragma unroll
        for (int j = 0; j < 2; ++j) {
          int row = j * 32 + srow;
          gload_lds16(kg + row * 128 + ((sc2 ^ (row & 7)) * 16),
                      Ks[bu] + j * 4096 + tid * 16);
        }
#pragma unroll
        for (int j = 0; j < 2; ++j) {
          int row = j * 32 + srow;
          gload_lds16(vg + row * 2048 + ((sc2 ^ (row & 7)) * 16),
                      Vs[bu] + j * 4096 + tid * 16);
        }
      }
      asm volatile("s_waitcnt vmcnt(8)" ::: "memory");  // current pair landed
    } else {
      asm volatile("s_waitcnt vmcnt(0)" ::: "memory");
    }
    __builtin_amdgcn_sched_barrier(0);

#pragma unroll
    for (int half = 0; half < 2; ++half) {
      const int bu = (2 * T + half) & 3;
      const char* Kc = Ks[bu];
      const char* Vc = Vs[bu];

      // QK^T (swapped): sa[qf][c] col(lane&15)=q-within-16, row(kgrp*4+r)=key
      f32x4 sa[2][4] = {};
      __builtin_amdgcn_s_setprio(1);
#pragma unroll
      for (int c = 0; c < 4; ++c) {
        int krow = c * 16 + lrow;
        bf16x8 k0 = *(const bf16x8*)(Kc + krow * 128 + ((kgrp ^ (krow & 7)) * 16));
        bf16x8 k1 = *(const bf16x8*)(Kc + krow * 128 + (((4 + kgrp) ^ (krow & 7)) * 16));
#pragma unroll
        for (int qf = 0; qf < 2; ++qf) {
          sa[qf][c] = __builtin_amdgcn_mfma_f32_16x16x32_bf16(k0, qa[qf][0], sa[qf][c], 0, 0, 0);
          sa[qf][c] = __builtin_amdgcn_mfma_f32_16x16x32_bf16(k1, qa[qf][1], sa[qf][c], 0, 0, 0);
        }
      }
      __builtin_amdgcn_s_setprio(0);

      // softmax numerator + P store (per-wave tile [32 q][64 key], swizzled)
#pragma unroll
      for (int qf = 0; qf < 2; ++qf) {
        int prow = qf * 16 + lrow;
        float rs = 0.f;
#pragma unroll
        for (int c = 0; c < 4; ++c) {
          bf16x4 pk;
#pragma unroll
          for (int r = 0; r < 4; ++r) {
            float p = exp2f(sa[qf][c][r]);
            rs += p;
            pk[r] = (bf16_t)p;
          }
          int chunk = (c * 2 + (kgrp >> 1)) ^ (prow & 7);
          *(bf16x4*)(Pw + prow * 128 + chunk * 16 + (kgrp & 1) * 8) = pk;
        }
        l_part[qf] += rs;
      }

      // PV
      __builtin_amdgcn_s_setprio(1);
#pragma unroll
      for (int kk = 0; kk < 2; ++kk) {
        bf16x8 pa[2];
#pragma unroll
        for (int qf = 0; qf < 2; ++qf) {
          int prow = qf * 16 + lrow;
          int pchunk = (kk * 4 + kgrp) ^ (prow & 7);
          pa[qf] = *(const bf16x8*)(Pw + prow * 128 + pchunk * 16);
        }
#pragma unroll
        for (int nfo = 0; nfo < 4; ++nfo) {
          int vrow = nfo * 16 + lrow;
          int vchunk = (kk * 4 + kgrp) ^ (vrow & 7);
          bf16x8 vb = *(const bf16x8*)(Vc + vrow * 128 + vchunk * 16);
#pragma unroll
          for (int qf = 0; qf < 2; ++qf)
            o[qf][nfo] = __builtin_amdgcn_mfma_f32_16x16x32_bf16(pa[qf], vb, o[qf][nfo], 0, 0, 0);
        }
      }
      __builtin_amdgcn_s_setprio(0);
    }
  }

  // epilogue
#pragma unroll
  for (int qf = 0; qf < 2; ++qf) {
    l_part[qf] += __shfl_xor(l_part[qf], 16, 64);
    l_part[qf] += __shfl_xor(l_part[qf], 32, 64);
  }
#pragma unroll
  for (int qf = 0; qf < 2; ++qf)
#pragma unroll
    for (int r = 0; r < 4; ++r) {
      float inv = 1.0f / __shfl(l_part[qf], kgrp * 4 + r, 64);
      int s = qbase + qf * 16 + kgrp * 4 + r;
#pragma unroll
      for (int nfo = 0; nfo < 4; ++nfo) {
        int d = nfo * 16 + lrow;
        attn_out[((b * 1024 + s) * 8 + h) * 64 + d] = (bf16_t)(o[qf][nfo][r] * inv);
      }
    }
}

// ---------------- out-proj: 64x128 tiles, 512 balanced blocks ----------------
// woT[512][512] (A, M=c) x attn[8192][512] (B, N=s) + x -> out. Quad-buffered
// depth-2, r7 ordering. 3 loads/tile/thread; vmcnt(6) = tile t complete.
__global__ void __launch_bounds__(256, 2) gemm_out_kernel(const bf16_t* __restrict__ woT,
                                                          const bf16_t* __restrict__ attn,
                                                          const float* __restrict__ x,
                                                          const float* __restrict__ bo,
                                                          float* __restrict__ out) {
  __shared__ bf16_t As[4][64 * 32];
  __shared__ bf16_t Bs[4][128 * 32];
  const int bn = blockIdx.x, bm = blockIdx.y;
  const bf16_t* Abase = woT + bm * 64 * 512;
  const bf16_t* Bbase = attn + bn * 128 * 512;
  const int tid = threadIdx.x;
  const int lane = tid & 63;
  const int wid = tid >> 6;
  const int wr = wid >> 1, wc = wid & 1;
  const int lrow = lane & 15;
  const int kgrp = lane >> 4;
  const int r0 = tid >> 2;
  const int cb = (tid & 3) * 16;
  f32x4 acc[2][4] = {};

#pragma unroll
  for (int p = 0; p < 2; ++p) {
    const int kt = p * 32;
    gload_lds16((const char*)(Abase + r0 * 512 + kt) + cb, (char*)As[p] + r0 * 64 + cb);
#pragma unroll
    for (int j = 0; j < 2; ++j) {
      int row = j * 64 + r0;
      gload_lds16((const char*)(Bbase + row * 512 + kt) + cb, (char*)Bs[p] + row * 64 + cb);
    }
  }

  for (int t = 0; t < 16; ++t) {
    const int cur = t & 3;
    if (t < 14) {
      const int nxt = (t + 2) & 3;
      const int kt = (t + 2) * 32;
      gload_lds16((const char*)(Abase + r0 * 512 + kt) + cb, (char*)As[nxt] + r0 * 64 + cb);
#pragma unroll
      for (int j = 0; j < 2; ++j) {
        int row = j * 64 + r0;
        gload_lds16((const char*)(Bbase + row * 512 + kt) + cb,
                    (char*)Bs[nxt] + row * 64 + cb);
      }
      asm volatile("s_waitcnt vmcnt(6)" ::: "memory");   // tile t complete
    } else if (t == 14) {
      asm volatile("s_waitcnt vmcnt(3)" ::: "memory");
    } else {
      asm volatile("s_waitcnt vmcnt(0)" ::: "memory");
    }
    __builtin_amdgcn_sched_barrier(0);
    __builtin_amdgcn_s_barrier();

    bf16x8 a[2], bfr[4];
#pragma unroll
    for (int mf = 0; mf < 2; ++mf)
      a[mf] = *(const bf16x8*)(As[cur] + (wr * 32 + mf * 16 + lrow) * 32 + kgrp * 8);
#pragma unroll
    for (int nf = 0; nf < 4; ++nf)
      bfr[nf] = *(const bf16x8*)(Bs[cur] + (wc * 64 + nf * 16 + lrow) * 32 + kgrp * 8);
    __builtin_amdgcn_s_setprio(1);
#pragma unroll
    for (int mf = 0; mf < 2; ++mf)
#pragma unroll
      for (int nf = 0; nf < 4; ++nf)
        acc[mf][nf] = __builtin_amdgcn_mfma_f32_16x16x32_bf16(a[mf], bfr[nf], acc[mf][nf], 0, 0, 0);
    __builtin_amdgcn_s_setprio(0);
  }

  const int c0 = bm * 64 + wr * 32;
  const int s0g = bn * 128 + wc * 64;
#pragma unroll
  for (int mf = 0; mf < 2; ++mf)
#pragma unroll
    for (int r = 0; r < 4; ++r) {
      int c = c0 + mf * 16 + kgrp * 4 + r;
      float bias = bo[c];
#pragma unroll
      for (int nf = 0; nf < 4; ++nf) {
        int n = s0g + nf * 16 + lrow;
        int b = n >> 10, s = n & 1023;
        int idx = (b * 512 + c) * 1024 + s;
        out[idx] = x[idx] + acc[mf][nf][r] + bias;
      }
    }
}

extern "C" void kernel_launch(void* const* d_in, const int* in_sizes, int n_in,
                              void* d_out, int out_size, void* d_ws, size_t ws_size,
                              hipStream_t stream) {
  const float* x  = (const float*)d_in[0];
  const float* wq = (const float*)d_in[1];
  const float* bq = (const float*)d_in[2];
  const float* wk = (const float*)d_in[3];
  const float* bk = (const float*)d_in[4];
  const float* wv = (const float*)d_in[5];
  const float* bv = (const float*)d_in[6];
  const float* wo = (const float*)d_in[7];
  const float* bo = (const float*)d_in[8];
  float* out = (float*)d_out;

  char* ws = (char*)d_ws;
  const size_t SZ_XR = (size_t)8192 * 512 * 2;         // 8 MB
  const size_t SZ_W  = (size_t)512 * 512 * 2;          // 0.5 MB
  const size_t SZ_T  = (size_t)8 * 8 * 1024 * 64 * 2;  // 8 MB
  bf16_t* xr   = (bf16_t*)(ws);
  bf16_t* wqT  = (bf16_t*)(ws + SZ_XR);                // wq/wk/wv contiguous [1536][512]
  bf16_t* wkT  = (bf16_t*)(ws + SZ_XR + SZ_W);
  bf16_t* wvT  = (bf16_t*)(ws + SZ_XR + 2 * SZ_W);
  bf16_t* woT  = (bf16_t*)(ws + SZ_XR + 3 * SZ_W);
  bf16_t* qd   = (bf16_t*)(ws + SZ_XR + 4 * SZ_W);
  bf16_t* kd   = (bf16_t*)(ws + SZ_XR + 4 * SZ_W + SZ_T);
  bf16_t* vtd  = (bf16_t*)(ws + SZ_XR + 4 * SZ_W + 2 * SZ_T);
  bf16_t* attn = (bf16_t*)(ws);                        // alias xr (dead by attn time)

  prep_kernel<<<dim3(1280), 256, 0, stream>>>(x, wq, wk, wv, wo, xr, wqT, wkT, wvT, woT);
  gemm_qkv_kernel<<<dim3(6, 64), 256, 0, stream>>>(xr, wqT, bq, bk, bv, qd, kd, vtd);
  attn_kernel<<<dim3(64, 8), 256, 0, stream>>>(qd, kd, vtd, attn);
  gemm_out_kernel<<<dim3(64, 8), 256, 0, stream>>>(woT, attn, x, bo, out);
}